// Round 8
// baseline (434.646 us; speedup 1.0000x reference)
//
#include <hip/hip_runtime.h>
#include <hip/hip_bf16.h>
#include <math.h>

#define T_DIM 512
#define B_DIM 32
#define V_DIM 4096
#define LMAX 32
#define S_DIM 65            // 2*LMAX+1
#define NEG (-1e30f)
#define EROWS 528           // T_DIM + 16 pad rows (staging reads row 512; finite poison, discarded)
#define LOG2E 1.4426950408889634f
#define LN2   0.6931471805599453f

// ---- raw hardware transcendentals (v_exp_f32 IS exp2; v_log_f32 IS log2) ----
__device__ __forceinline__ float fexp2(float x) {
#if __has_builtin(__builtin_amdgcn_exp2f)
    return __builtin_amdgcn_exp2f(x);
#else
    return exp2f(x);
#endif
}
__device__ __forceinline__ float flog2(float x) {
#if __has_builtin(__builtin_amdgcn_logf)
    return __builtin_amdgcn_logf(x);
#else
    return log2f(x);
#endif
}
// force global_load (vmcnt-only) for the init row
__device__ __forceinline__ float gload(const float* p) {
    return *(const __attribute__((address_space(1))) float*)((unsigned long long)p);
}
// async global->LDS DMA, 16B/lane: LDS dst = uniform base + lane*16; global src per-lane
__device__ __forceinline__ void load_lds16(const float* g, float* l) {
    __builtin_amdgcn_global_load_lds(
        (const __attribute__((address_space(1))) unsigned int*)(const void*)g,
        (__attribute__((address_space(3))) unsigned int*)(void*)l, 16, 0, 0);
}
__device__ __forceinline__ void load_lds4(const float* g, float* l) {
    __builtin_amdgcn_global_load_lds(
        (const __attribute__((address_space(1))) unsigned int*)(const void*)g,
        (__attribute__((address_space(3))) unsigned int*)(void*)l, 4, 0, 0);
}
__device__ __forceinline__ float lse2_2(float x, float y) {
    float m = fmaxf(x, y);
    return m + flog2(fexp2(x - m) + fexp2(y - m));
}
__device__ __forceinline__ float lse3_2(float x, float y, float z) {
    float m = fmaxf(x, fmaxf(y, z));   // fuses to v_max3_f32
    return m + flog2(fexp2(x - m) + fexp2(y - m) + fexp2(z - m));
}

// ---------------------------------------------------------------------------
// Kernel 0: extended labels + can_skip.
// ---------------------------------------------------------------------------
__global__ void k_ext(const int* __restrict__ labels,
                      const int* __restrict__ label_lens,
                      int total,
                      int* __restrict__ ext,
                      int* __restrict__ canskip) {
    int idx = blockIdx.x * blockDim.x + threadIdx.x;
    if (idx >= B_DIM * S_DIM) return;
    int b = idx / S_DIM;
    int s = idx % S_DIM;
    int off = 0;
    for (int i = 0; i < b; ++i) off += label_lens[i];
    int len = label_lens[b];

    auto getext = [&](int ss) -> int {
        if ((ss & 1) == 0) return 0;
        int j = ss >> 1;
        if (j >= len) return 0;
        int id = off + j;
        if (id > total - 1) id = total - 1;
        if (id < 0) id = 0;
        return labels[id];
    };

    int e = getext(s);
    ext[idx] = e;
    int cs = 0;
    if (s >= 2) {
        int em2 = getext(s - 2);
        cs = (e != 0 && e != em2) ? 1 : 0;
    }
    canskip[idx] = cs;
}

// ---------------------------------------------------------------------------
// Kernel 1 (unchanged this round): per (t,b) row: logZ via HW exp2/log2,
// gather emissions pre-scaled by log2(e):
//   emitA[b][t][0..64) , emit64[b][t]
// ---------------------------------------------------------------------------
__global__ __launch_bounds__(256) void k_logz_emit(const float* __restrict__ acts,
                                                   const int* __restrict__ ext,
                                                   float* __restrict__ emitA,
                                                   float* __restrict__ emit64) {
    int bid = blockIdx.x;              // = t*B + b
    int t = bid / B_DIM;
    int b = bid % B_DIM;
    const float* row = acts + (size_t)bid * V_DIM;
    int tid = threadIdx.x;

    const float4* row4 = reinterpret_cast<const float4*>(row);
    float4 v[4];
#pragma unroll
    for (int k = 0; k < 4; ++k) v[k] = row4[tid + k * 256];

    float mx = -INFINITY;
#pragma unroll
    for (int k = 0; k < 4; ++k)
        mx = fmaxf(mx, fmaxf(fmaxf(v[k].x, v[k].y), fmaxf(v[k].z, v[k].w)));
#pragma unroll
    for (int off = 32; off > 0; off >>= 1) mx = fmaxf(mx, __shfl_xor(mx, off));

    __shared__ float smax[4], ssum[4];
    int wave = tid >> 6, lane = tid & 63;
    if (lane == 0) smax[wave] = mx;
    __syncthreads();
    mx = fmaxf(fmaxf(smax[0], smax[1]), fmaxf(smax[2], smax[3]));

    float mxL = mx * LOG2E;
    float s = 0.f;
#pragma unroll
    for (int k = 0; k < 4; ++k) {
        s += fexp2(fmaf(v[k].x, LOG2E, -mxL));
        s += fexp2(fmaf(v[k].y, LOG2E, -mxL));
        s += fexp2(fmaf(v[k].z, LOG2E, -mxL));
        s += fexp2(fmaf(v[k].w, LOG2E, -mxL));
    }
#pragma unroll
    for (int off = 32; off > 0; off >>= 1) s += __shfl_xor(s, off);
    if (lane == 0) ssum[wave] = s;
    __syncthreads();
    s = ssum[0] + ssum[1] + ssum[2] + ssum[3];

    float logZ2 = mxL + flog2(s);

    if (tid < 64) {
        int lab = ext[b * S_DIM + tid];
        emitA[((size_t)b * EROWS + t) * 64 + tid] = fmaf(row[lab], LOG2E, -logZ2);
    } else if (tid == 64) {
        emit64[(size_t)b * EROWS + t] = fmaf(row[0], LOG2E, -logZ2);
    }
}

// ---------------------------------------------------------------------------
// Kernel 2: CTC forward, LDS-staged. One wave/example, lane=state.
// Emissions staged 64 timesteps at a time into double-buffered LDS via
// global_load_lds (one vmcnt(0) per 64 steps). Inner loop = 4 ds_read_b32
// (conflict-free) + 4 ds_bpermute + pure-VALU log2-domain lse chain.
// Two time-steps per shuffle round. State-64 chain gated wave-uniformly
// (only len==32 blocks pay it). Fixed 8x32-round trip; ragged lengths via
// wave-uniform freeze selects.
// ---------------------------------------------------------------------------
__global__ __launch_bounds__(64) void k_forward(const float* __restrict__ emitA,
                                                const float* __restrict__ emit64,
                                                const int* __restrict__ canskip,
                                                const int* __restrict__ act_lens,
                                                const int* __restrict__ label_lens,
                                                float* __restrict__ losses) {
    __shared__ float bufA[2][64 * 64];   // [slot][row r][lane] ; r = t - (64g+1)
    __shared__ float buf64[2][64];

    int b = blockIdx.x;
    int l = threadIdx.x;           // lane == state index (0..63)
    int len = label_lens[b];
    int alen = act_lens[b];
    int Svalid = 2 * len + 1;
    bool validS  = l < Svalid;
    bool validM1 = (l >= 1) && (l - 1 < Svalid);
    bool validM2 = (l >= 2) && (l - 2 < Svalid);
    bool has64 = (len == LMAX);
    const int* csb = canskip + b * S_DIM;
    bool skipS  = csb[l] != 0;
    bool skipM1 = (l >= 1) ? (csb[l - 1] != 0) : false;
    bool skipM2 = (l >= 2) ? (csb[l - 2] != 0) : false;

    const float* pb  = emitA + (size_t)b * EROWS * 64;
    const float* p64 = emit64 + (size_t)b * EROWS;
    int lm1 = (l >= 1) ? l - 1 : 0;
    int lm2 = (l >= 2) ? l - 2 : 0;

    // stage group g (rows t = 64g+1 .. 64g+64) into slot s
    auto stage = [&](int g, int s) {
        const float* gsrc = pb + (size_t)(64 * g + 1) * 64;
#pragma unroll
        for (int j = 0; j < 16; ++j)
            load_lds16(gsrc + j * 256 + l * 4, &bufA[s][j * 256]);
        if (has64)
            load_lds4(p64 + 64 * g + 1 + l, &buf64[s][0]);
    };

    float a   = (l <= 1) ? gload(pb + l) : NEG;   // t=0 init (l<=1 always valid)
    float a64 = NEG;                              // meaningful in lane 63 only

    stage(0, 0);
    asm volatile("s_waitcnt vmcnt(0)" ::: "memory");

    for (int g = 0; g < 8; ++g) {
        int cur = g & 1;
        if (g < 7) stage(g + 1, cur ^ 1);        // in flight during compute

#pragma unroll 4
        for (int j = 0; j < 32; ++j) {
            int t0 = 64 * g + 1 + 2 * j;         // this round: steps t0, t0+1
            const float* base = &bufA[cur][2 * j * 64];
            float c0  = base[l];
            float cm1 = base[lm1];
            float cm2 = base[lm2];
            float c1  = base[64 + l];

            float am1 = __shfl_up(a, 1); am1 = (l >= 1) ? am1 : NEG;
            float am2 = __shfl_up(a, 2); am2 = (l >= 2) ? am2 : NEG;
            float am3 = __shfl_up(a, 3); am3 = (l >= 3) ? am3 : NEG;
            float am4 = __shfl_up(a, 4); am4 = (l >= 4) ? am4 : NEG;

            // step t0 (states s, s-1, s-2 computed in lane s)
            float b0 = lse3_2(a,   am1, skipS  ? am2 : NEG) + c0;
            b0 = validS ? b0 : NEG;
            float b1 = lse3_2(am1, am2, skipM1 ? am3 : NEG) + cm1;
            b1 = validM1 ? b1 : NEG;
            float b2 = lse3_2(am2, am3, skipM2 ? am4 : NEG) + cm2;
            b2 = validM2 ? b2 : NEG;
            // step t0+1
            float cc = lse3_2(b0, b1, skipS ? b2 : NEG) + c1;
            cc = validS ? cc : NEG;

            bool r1 = t0 < alen, r2 = (t0 + 1) < alen;   // wave-uniform
            if (has64) {                                  // wave-uniform gate
                float ca64 = buf64[cur][2 * j];
                float cb64 = buf64[cur][2 * j + 1];
                float t64a = lse2_2(a64, a) + ca64;       // lane 63's a = alpha[63]
                float t64b = lse2_2(t64a, b0) + cb64;
                a64 = r2 ? t64b : (r1 ? t64a : a64);
            }
            a = r2 ? cc : (r1 ? b0 : a);
        }
        asm volatile("s_waitcnt vmcnt(0)" ::: "memory");  // next slot ready
    }

    // loss = -ln2 * log2addexp(alpha[end], alpha[end-1]), end = 2*len
    int end = 2 * len;
    float v64 = __shfl(a64, 63);
    float ae  = __shfl(a, end & 63);
    float l1 = (end == 64) ? v64 : ae;
    float l2 = __shfl(a, end - 1);                 // end-1 >= 31 (len >= 16)
    float m = fmaxf(l1, l2);
    float loss = -LN2 * (m + flog2(fexp2(l1 - m) + fexp2(l2 - m)));
    if (l == 0) losses[b] = loss;
}

// ---------------------------------------------------------------------------
// Kernel 3: sum per-example losses -> d_out[0]
// ---------------------------------------------------------------------------
__global__ void k_sum(const float* __restrict__ losses, float* __restrict__ out) {
    int l = threadIdx.x;
    float v = (l < B_DIM) ? losses[l] : 0.f;
#pragma unroll
    for (int off = 32; off > 0; off >>= 1) v += __shfl_xor(v, off);
    if (l == 0) out[0] = v;
}

// ---------------------------------------------------------------------------
extern "C" void kernel_launch(void* const* d_in, const int* in_sizes, int n_in,
                              void* d_out, int out_size, void* d_ws, size_t ws_size,
                              hipStream_t stream) {
    const float* acts       = (const float*)d_in[0];
    const int*   labels     = (const int*)d_in[1];
    const int*   act_lens   = (const int*)d_in[2];
    const int*   label_lens = (const int*)d_in[3];
    int total_labels = in_sizes[1];

    char* ws = (char*)d_ws;
    // ext [B*S i32] | canskip [B*S i32] | losses [B f32] | emitA [B*EROWS*64 f32] | emit64 [B*EROWS f32]
    int*   ext     = (int*)(ws);
    int*   canskip = (int*)(ws + 8320);
    float* losses  = (float*)(ws + 16640);
    float* emitA   = (float*)(ws + 16768);
    float* emit64  = (float*)(ws + 16768 + (size_t)B_DIM * EROWS * 64 * 4);
    float* out     = (float*)d_out;

    k_ext<<<(B_DIM * S_DIM + 255) / 256, 256, 0, stream>>>(labels, label_lens,
                                                           total_labels, ext, canskip);
    k_logz_emit<<<T_DIM * B_DIM, 256, 0, stream>>>(acts, ext, emitA, emit64);
    k_forward<<<B_DIM, 64, 0, stream>>>(emitA, emit64, canskip, act_lens,
                                        label_lens, losses);
    k_sum<<<1, 64, 0, stream>>>(losses, out);
}

// Round 11
// 418.736 us; speedup vs baseline: 1.0380x; 1.0380x over previous
//
#include <hip/hip_runtime.h>
#include <hip/hip_bf16.h>
#include <math.h>

#define T_DIM 512
#define B_DIM 32
#define V_DIM 4096
#define LMAX 32
#define S_DIM 65            // 2*LMAX+1
#define NEG (-1e30f)
#define EROWS 528           // T_DIM + 16 pad rows (prefetch overrun reads finite poison, discarded)
#define RSTRIDE 66          // emission row stride: states 0..64 + 1 pad
#define LOG2E 1.4426950408889634f
#define LN2   0.6931471805599453f

// ---- raw hardware transcendentals (v_exp_f32 IS exp2; v_log_f32 IS log2) ----
__device__ __forceinline__ float fexp2(float x) {
#if __has_builtin(__builtin_amdgcn_exp2f)
    return __builtin_amdgcn_exp2f(x);
#else
    return exp2f(x);
#endif
}
__device__ __forceinline__ float flog2(float x) {
#if __has_builtin(__builtin_amdgcn_logf)
    return __builtin_amdgcn_logf(x);
#else
    return log2f(x);
#endif
}
// force global_load (vmcnt-only; keeps prefetch off the lgkm/shuffle chain)
__device__ __forceinline__ float gload(const float* p) {
    return *(const __attribute__((address_space(1))) float*)((unsigned long long)p);
}
// POD pair loaded as two adjacent scalar AS(1) loads (avoids HIP_vector_type
// addrspace copy-ctor issue; backend merges adjacent dwords where profitable)
struct F2 { float x, y; };
__device__ __forceinline__ F2 gload2(const float* p) {
    F2 r;
    r.x = gload(p);
    r.y = gload(p + 1);
    return r;
}
__device__ __forceinline__ float lse2_2(float x, float y) {
    float m = fmaxf(x, y);
    return m + flog2(fexp2(x - m) + fexp2(y - m));
}
__device__ __forceinline__ float lse3_2(float x, float y, float z) {
    float m = fmaxf(x, fmaxf(y, z));   // fuses to v_max3_f32
    return m + flog2(fexp2(x - m) + fexp2(y - m) + fexp2(z - m));
}

// ---------------------------------------------------------------------------
// Kernel 0: extended labels + can_skip.
// ---------------------------------------------------------------------------
__global__ void k_ext(const int* __restrict__ labels,
                      const int* __restrict__ label_lens,
                      int total,
                      int* __restrict__ ext,
                      int* __restrict__ canskip) {
    int idx = blockIdx.x * blockDim.x + threadIdx.x;
    if (idx >= B_DIM * S_DIM) return;
    int b = idx / S_DIM;
    int s = idx % S_DIM;
    int off = 0;
    for (int i = 0; i < b; ++i) off += label_lens[i];
    int len = label_lens[b];

    auto getext = [&](int ss) -> int {
        if ((ss & 1) == 0) return 0;
        int j = ss >> 1;
        if (j >= len) return 0;
        int id = off + j;
        if (id > total - 1) id = total - 1;
        if (id < 0) id = 0;
        return labels[id];
    };

    int e = getext(s);
    ext[idx] = e;
    int cs = 0;
    if (s >= 2) {
        int em2 = getext(s - 2);
        cs = (e != 0 && e != em2) ? 1 : 0;
    }
    canskip[idx] = cs;
}

// ---------------------------------------------------------------------------
// Kernel 1: per (t,b) row: logZ via HW exp2/log2; gather emissions pre-scaled
// by log2(e) into 66-wide rows: emitA[b][t][s], s = 0..64 (65 = pad).
// ---------------------------------------------------------------------------
__global__ __launch_bounds__(256) void k_logz_emit(const float* __restrict__ acts,
                                                   const int* __restrict__ ext,
                                                   float* __restrict__ emitA) {
    int bid = blockIdx.x;              // = t*B + b
    int t = bid / B_DIM;
    int b = bid % B_DIM;
    const float* row = acts + (size_t)bid * V_DIM;
    int tid = threadIdx.x;

    const float4* row4 = reinterpret_cast<const float4*>(row);
    float4 v[4];
#pragma unroll
    for (int k = 0; k < 4; ++k) v[k] = row4[tid + k * 256];

    float mx = -INFINITY;
#pragma unroll
    for (int k = 0; k < 4; ++k)
        mx = fmaxf(mx, fmaxf(fmaxf(v[k].x, v[k].y), fmaxf(v[k].z, v[k].w)));
#pragma unroll
    for (int off = 32; off > 0; off >>= 1) mx = fmaxf(mx, __shfl_xor(mx, off));

    __shared__ float smax[4], ssum[4];
    int wave = tid >> 6, lane = tid & 63;
    if (lane == 0) smax[wave] = mx;
    __syncthreads();
    mx = fmaxf(fmaxf(smax[0], smax[1]), fmaxf(smax[2], smax[3]));

    float mxL = mx * LOG2E;
    float s = 0.f;
#pragma unroll
    for (int k = 0; k < 4; ++k) {
        s += fexp2(fmaf(v[k].x, LOG2E, -mxL));
        s += fexp2(fmaf(v[k].y, LOG2E, -mxL));
        s += fexp2(fmaf(v[k].z, LOG2E, -mxL));
        s += fexp2(fmaf(v[k].w, LOG2E, -mxL));
    }
#pragma unroll
    for (int off = 32; off > 0; off >>= 1) s += __shfl_xor(s, off);
    if (lane == 0) ssum[wave] = s;
    __syncthreads();
    s = ssum[0] + ssum[1] + ssum[2] + ssum[3];

    float logZ2 = mxL + flog2(s);

    if (tid < S_DIM) {
        int lab = ext[b * S_DIM + tid];
        emitA[((size_t)b * EROWS + t) * RSTRIDE + tid] = fmaf(row[lab], LOG2E, -logZ2);
    }
}

// ---------------------------------------------------------------------------
// Kernel 2: CTC forward, pair-of-states-per-lane. One wave/example.
// Lane l holds alpha for states 2l (low) and 2l+1 (high); states 0..64 live
// in lanes 0..32 (state 64 = lane 32 low slot -> no side chain). Per time
// step the ONLY cross-lane value needed is old[2l-1] = previous lane's high
// slot: ONE __shfl_up per step (was 4). Even states are blanks (never skip)
// -> 2-way lse; odd states 3-way with canskip mask. Emissions stream as two
// scalar floats/lane/step via vmcnt-only global loads, 8-step prefetch window.
// ---------------------------------------------------------------------------
__global__ __launch_bounds__(64) void k_forward(const float* __restrict__ emitA,
                                                const int* __restrict__ canskip,
                                                const int* __restrict__ act_lens,
                                                const int* __restrict__ label_lens,
                                                float* __restrict__ losses) {
    int b = blockIdx.x;
    int l = threadIdx.x;               // lane: states 2l, 2l+1
    int len = label_lens[b];
    int alen = act_lens[b];
    int Svalid = 2 * len + 1;
    int sH = 2 * l + 1;
    bool validL = (2 * l) < Svalid;    // l <= len
    bool validH = sH < Svalid;         // l <  len
    const int* csb = canskip + b * S_DIM;
    int csi = (sH < S_DIM) ? sH : (S_DIM - 1);
    bool skipH = validH && (csb[csi] != 0);

    const float* pb = emitA + (size_t)b * EROWS * RSTRIDE;

    // t = 0 init: states 0,1 = emit0; rest NEG. Both live in lane 0.
    F2 e0 = gload2(pb + 2 * l);
    float aL = (l == 0) ? e0.x : NEG;
    float aH = (l == 0) ? e0.y : NEG;

    F2 c[8];
#pragma unroll
    for (int j = 0; j < 8; ++j)
        c[j] = gload2(pb + (size_t)(1 + j) * RSTRIDE + 2 * l);

    for (int w = 0; w < 64; ++w) {
        F2 n[8];
#pragma unroll
        for (int j = 0; j < 8; ++j)
            n[j] = gload2(pb + (size_t)(8 * (w + 1) + 1 + j) * RSTRIDE + 2 * l);

#pragma unroll
        for (int j = 0; j < 8; ++j) {
            int t = 8 * w + 1 + j;
            float pm1 = __shfl_up(aH, 1);          // old[2l-1]
            pm1 = (l >= 1) ? pm1 : NEG;
            float nL = lse2_2(aL, pm1) + c[j].x;                      // blank: no skip
            nL = validL ? nL : NEG;
            float nH = lse3_2(aH, aL, skipH ? pm1 : NEG) + c[j].y;    // label state
            nH = validH ? nH : NEG;
            bool run = t < alen;                   // wave-uniform freeze
            aL = run ? nL : aL;
            aH = run ? nH : aH;
        }
#pragma unroll
        for (int j = 0; j < 8; ++j) c[j] = n[j];
    }

    // loss = -ln2 * log2addexp(alpha[end], alpha[end-1]), end = 2*len (even)
    int le = len;                       // lane holding state end=2*len as LOW slot
    float l1 = __shfl(aL, le);
    float l2 = __shfl(aH, le - 1);      // state end-1 (odd) = high slot of lane le-1
    float m = fmaxf(l1, l2);
    float loss = -LN2 * (m + flog2(fexp2(l1 - m) + fexp2(l2 - m)));
    if (l == 0) losses[b] = loss;
}

// ---------------------------------------------------------------------------
// Kernel 3: sum per-example losses -> d_out[0]
// ---------------------------------------------------------------------------
__global__ void k_sum(const float* __restrict__ losses, float* __restrict__ out) {
    int l = threadIdx.x;
    float v = (l < B_DIM) ? losses[l] : 0.f;
#pragma unroll
    for (int off = 32; off > 0; off >>= 1) v += __shfl_xor(v, off);
    if (l == 0) out[0] = v;
}

// ---------------------------------------------------------------------------
extern "C" void kernel_launch(void* const* d_in, const int* in_sizes, int n_in,
                              void* d_out, int out_size, void* d_ws, size_t ws_size,
                              hipStream_t stream) {
    const float* acts       = (const float*)d_in[0];
    const int*   labels     = (const int*)d_in[1];
    const int*   act_lens   = (const int*)d_in[2];
    const int*   label_lens = (const int*)d_in[3];
    int total_labels = in_sizes[1];

    char* ws = (char*)d_ws;
    // ext [B*S i32] | canskip [B*S i32] | losses [B f32] | emitA [B*EROWS*66 f32]
    int*   ext     = (int*)(ws);
    int*   canskip = (int*)(ws + 8320);
    float* losses  = (float*)(ws + 16640);
    float* emitA   = (float*)(ws + 16768);
    float* out     = (float*)d_out;

    k_ext<<<(B_DIM * S_DIM + 255) / 256, 256, 0, stream>>>(labels, label_lens,
                                                           total_labels, ext, canskip);
    k_logz_emit<<<T_DIM * B_DIM, 256, 0, stream>>>(acts, ext, emitA);
    k_forward<<<B_DIM, 64, 0, stream>>>(emitA, canskip, act_lens,
                                        label_lens, losses);
    k_sum<<<1, 64, 0, stream>>>(losses, out);
}